// Round 26
// baseline (101.631 us; speedup 1.0000x reference)
//
#include <hip/hip_runtime.h>

// ROUND 26: proj v3 — zero-LDS fragment-direct GEMM. r25's BN-split re-read
// x 3x (201 MB -> 40 us L3/HBM-bound). Now: wave owns 16 rows x all 192 cols,
// A-frags direct from x (f32->bf16 in-reg), B-frags direct from L2-resident
// Wt, no barriers; K-split x2 across 2 waves/block -> 2048 waves, x read ONCE.
// attn (r24: XCD-affinity + swapped QK^T + pairing) and transpose unchanged.
// Contract (r17): f32 in dict-order, W [1024][64] k-major, causal/S per
// batch, scale 1/8, f32 out [B,S,D].
// ws: Wt 384KB | qg 2MB | kg 2MB | vtg[8][64][2048] 2MB = 6.4 MB.

#define BATCH 8
#define SEQ   2048
#define EMB   1024
#define HD    64
#define QBLK  16
#define NSPL  8

typedef __attribute__((ext_vector_type(8))) short short8;
typedef __attribute__((ext_vector_type(4))) short short4v;
typedef __attribute__((ext_vector_type(4))) float f32x4;

static __device__ __forceinline__ short f2bf(float f) {
    union { float f; unsigned int i; } c;
    c.f = f;
    unsigned int r = c.i + 0x7fff + ((c.i >> 16) & 1);  // RNE
    return (short)(r >> 16);
}

// ---------------------------------------------------------------------------
// Kernel 1: transpose+convert Wq|Wk|Wv f32[1024][64] -> Wt bf16[192][1024]
// ---------------------------------------------------------------------------
__global__ __launch_bounds__(256) void transpose_w(
    const float* __restrict__ Wq, const float* __restrict__ Wk,
    const float* __restrict__ Wv, short* __restrict__ Wt) {
    __shared__ short tileT[64][72];
    int bid = blockIdx.x;
    int p = bid >> 4, kt = bid & 15;
    const float* W = (p == 0) ? Wq : ((p == 1) ? Wk : Wv);
    int t = threadIdx.x;
    int k0 = kt * 64;
    int row = t >> 2, c0 = (t & 3) * 16;
    const float* src = W + (long)(k0 + row) * HD + c0;
    #pragma unroll
    for (int j = 0; j < 16; ++j)
        tileT[c0 + j][row] = f2bf(src[j]);
    __syncthreads();
    int n = t >> 2, ks = (t & 3) * 16;
    short8 o0 = *(const short8*)(&tileT[n][ks]);
    short8 o1 = *(const short8*)(&tileT[n][ks + 8]);
    *(short8*)(Wt + (long)(p * 64 + n) * EMB + k0 + ks)     = o0;
    *(short8*)(Wt + (long)(p * 64 + n) * EMB + k0 + ks + 8) = o1;
}

// ---------------------------------------------------------------------------
// Kernel 2: proj v3. 1024 blocks x 128 thr (2 waves). Block owns 16 rows;
// wave w computes K-half w. A-frags from x (f32->bf16), B-frags from Wt (L2).
// No staging, no barriers in the K-loop. Merge + epilogue by wave 0.
// ---------------------------------------------------------------------------
__global__ __launch_bounds__(128, 4) void proj_mfma(
    const float* __restrict__ x, const short* __restrict__ Wt,
    short* __restrict__ qg, short* __restrict__ kg, short* __restrict__ vtg) {
    __shared__ float accL[12][4][64];   // wave-1 partials
    __shared__ short vL[64][20];        // v transpose staging

    int m0 = blockIdx.x * 16;
    int t = threadIdx.x;
    int w = t >> 6, l = t & 63;
    int ll = l & 15, lg = l >> 4;

    f32x4 acc[12] = {};

    const float* xrow = x + (long)(m0 + ll) * EMB;
    int kbeg = w * 512, kend = kbeg + 512;

    for (int k0 = kbeg; k0 < kend; k0 += 32) {
        // A-frag: this lane's 8 x values (f32 -> bf16)
        f32x4 a0 = *(const f32x4*)(xrow + k0 + lg * 8);
        f32x4 a1 = *(const f32x4*)(xrow + k0 + lg * 8 + 4);
        short8 af;
        #pragma unroll
        for (int j = 0; j < 4; ++j) { af[j] = f2bf(a0[j]); af[4 + j] = f2bf(a1[j]); }
        // B-frags direct from Wt (L2-resident), 12 independent MFMAs
        #pragma unroll
        for (int ni = 0; ni < 12; ++ni) {
            short8 bf = *(const short8*)(Wt + (long)(ni * 16 + ll) * EMB + k0 + lg * 8);
            acc[ni] = __builtin_amdgcn_mfma_f32_16x16x32_bf16(af, bf, acc[ni], 0, 0, 0);
        }
    }

    if (w == 1) {
        #pragma unroll
        for (int ni = 0; ni < 12; ++ni)
            #pragma unroll
            for (int r = 0; r < 4; ++r)
                accL[ni][r][l] = acc[ni][r];
    }
    __syncthreads();
    if (w == 0) {
        #pragma unroll
        for (int ni = 0; ni < 12; ++ni)
            #pragma unroll
            for (int r = 0; r < 4; ++r)
                acc[ni][r] += accL[ni][r][l];

        const float cs = 0.125f * 1.44269504088896f;
        int mrow = m0 + lg * 4;
        #pragma unroll
        for (int ni = 0; ni < 4; ++ni)
            #pragma unroll
            for (int r = 0; r < 4; ++r)
                qg[(long)(mrow + r) * HD + ni * 16 + ll] = f2bf(acc[ni][r] * cs);
        #pragma unroll
        for (int ni = 4; ni < 8; ++ni)
            #pragma unroll
            for (int r = 0; r < 4; ++r)
                kg[(long)(mrow + r) * HD + (ni - 4) * 16 + ll] = f2bf(acc[ni][r]);
        #pragma unroll
        for (int ni = 8; ni < 12; ++ni)
            #pragma unroll
            for (int r = 0; r < 4; ++r)
                vL[(ni - 8) * 16 + ll][lg * 4 + r] = f2bf(acc[ni][r]);
        // same-wave LDS read-back (in-order), transposed store
        int b = m0 >> 11, s0 = m0 & 2047;
        int d = l;
        short8 v0 = *(const short8*)(&vL[d][0]);
        short8 v1 = *(const short8*)(&vL[d][8]);
        *(short8*)(vtg + ((long)b * HD + d) * SEQ + s0)     = v0;
        *(short8*)(vtg + ((long)b * HD + d) * SEQ + s0 + 8) = v1;
    }
}

// ---------------------------------------------------------------------------
// Kernel 3: paired-tile attention, swapped QK^T, XCD-affinity grid (r24).
// 512 1D blocks: b = id&7 (XCD), pair = id>>3. 512 thr = 8 waves.
// ---------------------------------------------------------------------------
__global__ __launch_bounds__(512, 4) void attn_mfma(
    const short* __restrict__ qg, const short* __restrict__ kg,
    const short* __restrict__ vtg, float* __restrict__ out) {
    __shared__ short PLA[NSPL][16][72];
    __shared__ short PLB[NSPL][16][72];
    __shared__ float pO[NSPL][16][65];
    __shared__ float pLs[NSPL][16];

    int b    = blockIdx.x & 7;
    int pair = blockIdx.x >> 3;
    int qtA = pair;
    int qtB = 127 - pair;
    int q0A = qtA * QBLK, q0B = qtB * QBLK;
    int t = threadIdx.x;
    int w = t >> 6, l = t & 63;
    int ll = l & 15, lg = l >> 4;

    const short* qb = qg + (long)b * SEQ * HD;
    const short* kb = kg + (long)b * SEQ * HD;
    const short* vb = vtg + (long)b * HD * SEQ;

    short8 qfA[2], qfB[2];
    #pragma unroll
    for (int ks = 0; ks < 2; ++ks) {
        qfA[ks] = *(const short8*)(qb + (long)(q0A + ll) * HD + ks * 32 + lg * 8);
        qfB[ks] = *(const short8*)(qb + (long)(q0B + ll) * HD + ks * 32 + lg * 8);
    }

    f32x4 accA[4] = {}, accB[4] = {};
    float psA = 0.f, psB = 0.f;

    int nkvB = q0B / 64 + 1;

    for (int kt = w; kt < nkvB; kt += NSPL) {
        int kv0 = kt * 64;
        bool maskA = (kv0 + 63) > q0A;
        bool maskB = (kv0 + 63) > q0B;

        #pragma unroll
        for (int n = 0; n < 4; ++n) {
            const short* kr = kb + (long)(kv0 + n * 16 + ll) * HD + lg * 8;
            short8 kf0 = *(const short8*)(kr);
            short8 kf1 = *(const short8*)(kr + 32);
            int kvb = kv0 + n * 16 + lg * 4;

            f32x4 sA = {};
            sA = __builtin_amdgcn_mfma_f32_16x16x32_bf16(kf0, qfA[0], sA, 0, 0, 0);
            sA = __builtin_amdgcn_mfma_f32_16x16x32_bf16(kf1, qfA[1], sA, 0, 0, 0);
            short4v pkA;
            #pragma unroll
            for (int r = 0; r < 4; ++r) {
                float pv = __builtin_amdgcn_exp2f(sA[r]);
                if (maskA && (kvb + r > q0A + ll)) pv = 0.f;
                psA += pv;
                pkA[r] = f2bf(pv);
            }
            *(short4v*)(&PLA[w][ll][n * 16 + lg * 4]) = pkA;

            f32x4 sB = {};
            sB = __builtin_amdgcn_mfma_f32_16x16x32_bf16(kf0, qfB[0], sB, 0, 0, 0);
            sB = __builtin_amdgcn_mfma_f32_16x16x32_bf16(kf1, qfB[1], sB, 0, 0, 0);
            short4v pkB;
            #pragma unroll
            for (int r = 0; r < 4; ++r) {
                float pv = __builtin_amdgcn_exp2f(sB[r]);
                if (maskB && (kvb + r > q0B + ll)) pv = 0.f;
                psB += pv;
                pkB[r] = f2bf(pv);
            }
            *(short4v*)(&PLB[w][ll][n * 16 + lg * 4]) = pkB;
        }

        #pragma unroll
        for (int ks = 0; ks < 2; ++ks) {
            short8 pfA = *(const short8*)(&PLA[w][ll][ks * 32 + lg * 8]);
            short8 pfB = *(const short8*)(&PLB[w][ll][ks * 32 + lg * 8]);
            #pragma unroll
            for (int nd = 0; nd < 4; ++nd) {
                short8 vf = *(const short8*)(vb + (long)(nd * 16 + ll) * SEQ + kv0 + ks * 32 + lg * 8);
                accA[nd] = __builtin_amdgcn_mfma_f32_16x16x32_bf16(pfA, vf, accA[nd], 0, 0, 0);
                accB[nd] = __builtin_amdgcn_mfma_f32_16x16x32_bf16(pfB, vf, accB[nd], 0, 0, 0);
            }
        }
    }

    psA += __shfl_xor(psA, 16, 64);
    psA += __shfl_xor(psA, 32, 64);
    psB += __shfl_xor(psB, 16, 64);
    psB += __shfl_xor(psB, 32, 64);

    // ---- tile A ----
    #pragma unroll
    for (int nd = 0; nd < 4; ++nd)
        #pragma unroll
        for (int r = 0; r < 4; ++r)
            pO[w][lg * 4 + r][nd * 16 + ll] = accA[nd][r];
    if (lg == 0) pLs[w][ll] = psA;
    __syncthreads();
    {
        int q = t >> 5, d0 = (t & 31) * 2;
        float L = 0.f, o0 = 0.f, o1 = 0.f;
        #pragma unroll
        for (int w2 = 0; w2 < NSPL; ++w2) {
            L  += pLs[w2][q];
            o0 += pO[w2][q][d0];
            o1 += pO[w2][q][d0 + 1];
        }
        float inv = 1.0f / L;
        float* dst = out + (long)b * SEQ * HD + (long)(q0A + q) * HD + d0;
        dst[0] = o0 * inv; dst[1] = o1 * inv;
    }
    __syncthreads();

    // ---- tile B ----
    #pragma unroll
    for (int nd = 0; nd < 4; ++nd)
        #pragma unroll
        for (int r = 0; r < 4; ++r)
            pO[w][lg * 4 + r][nd * 16 + ll] = accB[nd][r];
    if (lg == 0) pLs[w][ll] = psB;
    __syncthreads();
    {
        int q = t >> 5, d0 = (t & 31) * 2;
        float L = 0.f, o0 = 0.f, o1 = 0.f;
        #pragma unroll
        for (int w2 = 0; w2 < NSPL; ++w2) {
            L  += pLs[w2][q];
            o0 += pO[w2][q][d0];
            o1 += pO[w2][q][d0 + 1];
        }
        float inv = 1.0f / L;
        float* dst = out + (long)b * SEQ * HD + (long)(q0B + q) * HD + d0;
        dst[0] = o0 * inv; dst[1] = o1 * inv;
    }
}

// ---------------------------------------------------------------------------
extern "C" void kernel_launch(void* const* d_in, const int* in_sizes, int n_in,
                              void* d_out, int out_size, void* d_ws, size_t ws_size,
                              hipStream_t stream) {
    const float* x  = (const float*)d_in[0];
    const float* Wq = (const float*)d_in[1];
    const float* Wk = (const float*)d_in[2];
    const float* Wv = (const float*)d_in[3];
    float* outp = (float*)d_out;

    short* Wt  = (short*)d_ws;                                  // 384 KB
    short* qg  = (short*)((char*)d_ws + 393216);                // 2 MB
    short* kg  = (short*)((char*)d_ws + 393216 + 2097152);      // 2 MB
    short* vtg = (short*)((char*)d_ws + 393216 + 2 * 2097152);  // 2 MB

    transpose_w<<<48, 256, 0, stream>>>(Wq, Wk, Wv, Wt);
    proj_mfma<<<BATCH * SEQ / 16, 128, 0, stream>>>(x, Wt, qg, kg, vtg);
    attn_mfma<<<SEQ / QBLK / 2 * BATCH, 512, 0, stream>>>(qg, kg, vtg, outp);
}

// Round 27
// 93.713 us; speedup vs baseline: 1.0845x; 1.0845x over previous
//
#include <hip/hip_runtime.h>

// ROUND 27: proj v4 — fragment-direct (r26) with 4-way K-split per block:
// 256 thr = 4 waves, wave w owns K-quarter; grid 1024 -> 16 waves/CU
// (r26 was 8: 2-wave blocks couldn't hide the x-load latency chain).
// Partial-acc merge in LDS (1 barrier), wave 0 does epilogue.
// x read ONCE (r26 property kept), W L2-resident.
// attn (r24: XCD-affinity + swapped QK^T + pairing) and transpose unchanged.
// Contract (r17): f32 in dict-order, W [1024][64] k-major, causal/S per
// batch, scale 1/8, f32 out [B,S,D].
// ws: Wt 384KB | qg 2MB | kg 2MB | vtg[8][64][2048] 2MB = 6.4 MB.

#define BATCH 8
#define SEQ   2048
#define EMB   1024
#define HD    64
#define QBLK  16
#define NSPL  8

typedef __attribute__((ext_vector_type(8))) short short8;
typedef __attribute__((ext_vector_type(4))) short short4v;
typedef __attribute__((ext_vector_type(4))) float f32x4;

static __device__ __forceinline__ short f2bf(float f) {
    union { float f; unsigned int i; } c;
    c.f = f;
    unsigned int r = c.i + 0x7fff + ((c.i >> 16) & 1);  // RNE
    return (short)(r >> 16);
}

// ---------------------------------------------------------------------------
// Kernel 1: transpose+convert Wq|Wk|Wv f32[1024][64] -> Wt bf16[192][1024]
// ---------------------------------------------------------------------------
__global__ __launch_bounds__(256) void transpose_w(
    const float* __restrict__ Wq, const float* __restrict__ Wk,
    const float* __restrict__ Wv, short* __restrict__ Wt) {
    __shared__ short tileT[64][72];
    int bid = blockIdx.x;
    int p = bid >> 4, kt = bid & 15;
    const float* W = (p == 0) ? Wq : ((p == 1) ? Wk : Wv);
    int t = threadIdx.x;
    int k0 = kt * 64;
    int row = t >> 2, c0 = (t & 3) * 16;
    const float* src = W + (long)(k0 + row) * HD + c0;
    #pragma unroll
    for (int j = 0; j < 16; ++j)
        tileT[c0 + j][row] = f2bf(src[j]);
    __syncthreads();
    int n = t >> 2, ks = (t & 3) * 16;
    short8 o0 = *(const short8*)(&tileT[n][ks]);
    short8 o1 = *(const short8*)(&tileT[n][ks + 8]);
    *(short8*)(Wt + (long)(p * 64 + n) * EMB + k0 + ks)     = o0;
    *(short8*)(Wt + (long)(p * 64 + n) * EMB + k0 + ks + 8) = o1;
}

// ---------------------------------------------------------------------------
// Kernel 2: proj v4. 1024 blocks x 256 thr (4 waves). Block owns 16 rows;
// wave w computes K-quarter w (8 iters). A-frags from x (f32->bf16),
// B-frags from Wt (L2). No staging; merge partials in LDS; wave 0 epilogue.
// ---------------------------------------------------------------------------
__global__ __launch_bounds__(256, 4) void proj_mfma(
    const float* __restrict__ x, const short* __restrict__ Wt,
    short* __restrict__ qg, short* __restrict__ kg, short* __restrict__ vtg) {
    __shared__ float accL[3][12][4][64];   // waves 1..3 partials (36 KB)
    __shared__ short vL[64][20];           // v transpose staging

    int m0 = blockIdx.x * 16;
    int t = threadIdx.x;
    int w = t >> 6, l = t & 63;
    int ll = l & 15, lg = l >> 4;

    f32x4 acc[12] = {};

    const float* xrow = x + (long)(m0 + ll) * EMB;
    int kbeg = w * 256;

    #pragma unroll 2
    for (int ki = 0; ki < 8; ++ki) {
        int k0 = kbeg + ki * 32;
        f32x4 a0 = *(const f32x4*)(xrow + k0 + lg * 8);
        f32x4 a1 = *(const f32x4*)(xrow + k0 + lg * 8 + 4);
        short8 af;
        #pragma unroll
        for (int j = 0; j < 4; ++j) { af[j] = f2bf(a0[j]); af[4 + j] = f2bf(a1[j]); }
        #pragma unroll
        for (int ni = 0; ni < 12; ++ni) {
            short8 bf = *(const short8*)(Wt + (long)(ni * 16 + ll) * EMB + k0 + lg * 8);
            acc[ni] = __builtin_amdgcn_mfma_f32_16x16x32_bf16(af, bf, acc[ni], 0, 0, 0);
        }
    }

    if (w != 0) {
        #pragma unroll
        for (int ni = 0; ni < 12; ++ni)
            #pragma unroll
            for (int r = 0; r < 4; ++r)
                accL[w - 1][ni][r][l] = acc[ni][r];
    }
    __syncthreads();
    if (w == 0) {
        #pragma unroll
        for (int w2 = 0; w2 < 3; ++w2)
            #pragma unroll
            for (int ni = 0; ni < 12; ++ni)
                #pragma unroll
                for (int r = 0; r < 4; ++r)
                    acc[ni][r] += accL[w2][ni][r][l];

        const float cs = 0.125f * 1.44269504088896f;
        int mrow = m0 + lg * 4;
        #pragma unroll
        for (int ni = 0; ni < 4; ++ni)
            #pragma unroll
            for (int r = 0; r < 4; ++r)
                qg[(long)(mrow + r) * HD + ni * 16 + ll] = f2bf(acc[ni][r] * cs);
        #pragma unroll
        for (int ni = 4; ni < 8; ++ni)
            #pragma unroll
            for (int r = 0; r < 4; ++r)
                kg[(long)(mrow + r) * HD + (ni - 4) * 16 + ll] = f2bf(acc[ni][r]);
        #pragma unroll
        for (int ni = 8; ni < 12; ++ni)
            #pragma unroll
            for (int r = 0; r < 4; ++r)
                vL[(ni - 8) * 16 + ll][lg * 4 + r] = f2bf(acc[ni][r]);
        // same-wave LDS read-back (in-order), transposed store
        int b = m0 >> 11, s0 = m0 & 2047;
        int d = l;
        short8 v0 = *(const short8*)(&vL[d][0]);
        short8 v1 = *(const short8*)(&vL[d][8]);
        *(short8*)(vtg + ((long)b * HD + d) * SEQ + s0)     = v0;
        *(short8*)(vtg + ((long)b * HD + d) * SEQ + s0 + 8) = v1;
    }
}

// ---------------------------------------------------------------------------
// Kernel 3: paired-tile attention, swapped QK^T, XCD-affinity grid (r24).
// 512 1D blocks: b = id&7 (XCD), pair = id>>3. 512 thr = 8 waves.
// ---------------------------------------------------------------------------
__global__ __launch_bounds__(512, 4) void attn_mfma(
    const short* __restrict__ qg, const short* __restrict__ kg,
    const short* __restrict__ vtg, float* __restrict__ out) {
    __shared__ short PLA[NSPL][16][72];
    __shared__ short PLB[NSPL][16][72];
    __shared__ float pO[NSPL][16][65];
    __shared__ float pLs[NSPL][16];

    int b    = blockIdx.x & 7;
    int pair = blockIdx.x >> 3;
    int qtA = pair;
    int qtB = 127 - pair;
    int q0A = qtA * QBLK, q0B = qtB * QBLK;
    int t = threadIdx.x;
    int w = t >> 6, l = t & 63;
    int ll = l & 15, lg = l >> 4;

    const short* qb = qg + (long)b * SEQ * HD;
    const short* kb = kg + (long)b * SEQ * HD;
    const short* vb = vtg + (long)b * HD * SEQ;

    short8 qfA[2], qfB[2];
    #pragma unroll
    for (int ks = 0; ks < 2; ++ks) {
        qfA[ks] = *(const short8*)(qb + (long)(q0A + ll) * HD + ks * 32 + lg * 8);
        qfB[ks] = *(const short8*)(qb + (long)(q0B + ll) * HD + ks * 32 + lg * 8);
    }

    f32x4 accA[4] = {}, accB[4] = {};
    float psA = 0.f, psB = 0.f;

    int nkvB = q0B / 64 + 1;

    for (int kt = w; kt < nkvB; kt += NSPL) {
        int kv0 = kt * 64;
        bool maskA = (kv0 + 63) > q0A;
        bool maskB = (kv0 + 63) > q0B;

        #pragma unroll
        for (int n = 0; n < 4; ++n) {
            const short* kr = kb + (long)(kv0 + n * 16 + ll) * HD + lg * 8;
            short8 kf0 = *(const short8*)(kr);
            short8 kf1 = *(const short8*)(kr + 32);
            int kvb = kv0 + n * 16 + lg * 4;

            f32x4 sA = {};
            sA = __builtin_amdgcn_mfma_f32_16x16x32_bf16(kf0, qfA[0], sA, 0, 0, 0);
            sA = __builtin_amdgcn_mfma_f32_16x16x32_bf16(kf1, qfA[1], sA, 0, 0, 0);
            short4v pkA;
            #pragma unroll
            for (int r = 0; r < 4; ++r) {
                float pv = __builtin_amdgcn_exp2f(sA[r]);
                if (maskA && (kvb + r > q0A + ll)) pv = 0.f;
                psA += pv;
                pkA[r] = f2bf(pv);
            }
            *(short4v*)(&PLA[w][ll][n * 16 + lg * 4]) = pkA;

            f32x4 sB = {};
            sB = __builtin_amdgcn_mfma_f32_16x16x32_bf16(kf0, qfB[0], sB, 0, 0, 0);
            sB = __builtin_amdgcn_mfma_f32_16x16x32_bf16(kf1, qfB[1], sB, 0, 0, 0);
            short4v pkB;
            #pragma unroll
            for (int r = 0; r < 4; ++r) {
                float pv = __builtin_amdgcn_exp2f(sB[r]);
                if (maskB && (kvb + r > q0B + ll)) pv = 0.f;
                psB += pv;
                pkB[r] = f2bf(pv);
            }
            *(short4v*)(&PLB[w][ll][n * 16 + lg * 4]) = pkB;
        }

        #pragma unroll
        for (int ks = 0; ks < 2; ++ks) {
            short8 pfA = *(const short8*)(&PLA[w][ll][ks * 32 + lg * 8]);
            short8 pfB = *(const short8*)(&PLB[w][ll][ks * 32 + lg * 8]);
            #pragma unroll
            for (int nd = 0; nd < 4; ++nd) {
                short8 vf = *(const short8*)(vb + (long)(nd * 16 + ll) * SEQ + kv0 + ks * 32 + lg * 8);
                accA[nd] = __builtin_amdgcn_mfma_f32_16x16x32_bf16(pfA, vf, accA[nd], 0, 0, 0);
                accB[nd] = __builtin_amdgcn_mfma_f32_16x16x32_bf16(pfB, vf, accB[nd], 0, 0, 0);
            }
        }
    }

    psA += __shfl_xor(psA, 16, 64);
    psA += __shfl_xor(psA, 32, 64);
    psB += __shfl_xor(psB, 16, 64);
    psB += __shfl_xor(psB, 32, 64);

    // ---- tile A ----
    #pragma unroll
    for (int nd = 0; nd < 4; ++nd)
        #pragma unroll
        for (int r = 0; r < 4; ++r)
            pO[w][lg * 4 + r][nd * 16 + ll] = accA[nd][r];
    if (lg == 0) pLs[w][ll] = psA;
    __syncthreads();
    {
        int q = t >> 5, d0 = (t & 31) * 2;
        float L = 0.f, o0 = 0.f, o1 = 0.f;
        #pragma unroll
        for (int w2 = 0; w2 < NSPL; ++w2) {
            L  += pLs[w2][q];
            o0 += pO[w2][q][d0];
            o1 += pO[w2][q][d0 + 1];
        }
        float inv = 1.0f / L;
        float* dst = out + (long)b * SEQ * HD + (long)(q0A + q) * HD + d0;
        dst[0] = o0 * inv; dst[1] = o1 * inv;
    }
    __syncthreads();

    // ---- tile B ----
    #pragma unroll
    for (int nd = 0; nd < 4; ++nd)
        #pragma unroll
        for (int r = 0; r < 4; ++r)
            pO[w][lg * 4 + r][nd * 16 + ll] = accB[nd][r];
    if (lg == 0) pLs[w][ll] = psB;
    __syncthreads();
    {
        int q = t >> 5, d0 = (t & 31) * 2;
        float L = 0.f, o0 = 0.f, o1 = 0.f;
        #pragma unroll
        for (int w2 = 0; w2 < NSPL; ++w2) {
            L  += pLs[w2][q];
            o0 += pO[w2][q][d0];
            o1 += pO[w2][q][d0 + 1];
        }
        float inv = 1.0f / L;
        float* dst = out + (long)b * SEQ * HD + (long)(q0B + q) * HD + d0;
        dst[0] = o0 * inv; dst[1] = o1 * inv;
    }
}

// ---------------------------------------------------------------------------
extern "C" void kernel_launch(void* const* d_in, const int* in_sizes, int n_in,
                              void* d_out, int out_size, void* d_ws, size_t ws_size,
                              hipStream_t stream) {
    const float* x  = (const float*)d_in[0];
    const float* Wq = (const float*)d_in[1];
    const float* Wk = (const float*)d_in[2];
    const float* Wv = (const float*)d_in[3];
    float* outp = (float*)d_out;

    short* Wt  = (short*)d_ws;                                  // 384 KB
    short* qg  = (short*)((char*)d_ws + 393216);                // 2 MB
    short* kg  = (short*)((char*)d_ws + 393216 + 2097152);      // 2 MB
    short* vtg = (short*)((char*)d_ws + 393216 + 2 * 2097152);  // 2 MB

    transpose_w<<<48, 256, 0, stream>>>(Wq, Wk, Wv, Wt);
    proj_mfma<<<BATCH * SEQ / 16, 256, 0, stream>>>(x, Wt, qg, kg, vtg);
    attn_mfma<<<SEQ / QBLK / 2 * BATCH, 512, 0, stream>>>(qg, kg, vtg, outp);
}

// Round 28
// 71.667 us; speedup vs baseline: 1.4181x; 1.3076x over previous
//
#include <hip/hip_runtime.h>

// ROUND 28: W in MFMA-FRAGMENT ORDER. r27's proj was L2-request-bound: each
// B-load gathered 16 rows 2KB apart (64 cache lines/instr). Now transpose_w
// emits Wfrag[kblk][ni][lane][8] (lane = ll + 16*lg) so every B-load is one
// contiguous 1KB coalesced load -> 64x fewer L2 requests. x-loads row-direct
// (128B/row), unroll 4. K-split x4, 1024 blocks, 16 waves/CU (r27).
// attn (r24: XCD-affinity + swapped QK^T + pairing) and layout unchanged.
// Contract (r17): f32 in dict-order, W [1024][64] k-major, causal/S per
// batch, scale 1/8, f32 out [B,S,D].
// ws: Wfrag 384KB | qg 2MB | kg 2MB | vtg[8][64][2048] 2MB = 6.4 MB.

#define BATCH 8
#define SEQ   2048
#define EMB   1024
#define HD    64
#define QBLK  16
#define NSPL  8

typedef __attribute__((ext_vector_type(8))) short short8;
typedef __attribute__((ext_vector_type(4))) short short4v;
typedef __attribute__((ext_vector_type(4))) float f32x4;

static __device__ __forceinline__ short f2bf(float f) {
    union { float f; unsigned int i; } c;
    c.f = f;
    unsigned int r = c.i + 0x7fff + ((c.i >> 16) & 1);  // RNE
    return (short)(r >> 16);
}

// ---------------------------------------------------------------------------
// Kernel 1: Wq|Wk|Wv f32[1024][64] -> Wfrag bf16 in MFMA-fragment order:
// Wfrag[(kblk*12 + ni)*512 + lane*8 + j] = W_ni-row(ni*16 + (lane&15))
//   [k = kblk*32 + (lane>>4)*8 + j],  ni = p*4 + n64/16.
// 48 blocks (3 p x 16 ktiles), 256 thr; tileT[n][k] staged as before.
// ---------------------------------------------------------------------------
__global__ __launch_bounds__(256) void transpose_w(
    const float* __restrict__ Wq, const float* __restrict__ Wk,
    const float* __restrict__ Wv, short* __restrict__ Wfrag) {
    __shared__ short tileT[64][72];
    int bid = blockIdx.x;
    int p = bid >> 4, kt = bid & 15;
    const float* W = (p == 0) ? Wq : ((p == 1) ? Wk : Wv);
    int t = threadIdx.x;
    int k0 = kt * 64;
    int row = t >> 2, c0 = (t & 3) * 16;
    const float* src = W + (long)(k0 + row) * HD + c0;
    #pragma unroll
    for (int j = 0; j < 16; ++j)
        tileT[c0 + j][row] = f2bf(src[j]);
    __syncthreads();
    // write fragment order: thread t covers n64 = t>>2, k_local = (t&3)*16 .. +15
    int n64 = t >> 2;
    int ni = p * 4 + (n64 >> 4);
    int ll = n64 & 15;
    #pragma unroll
    for (int j2 = 0; j2 < 16; ++j2) {
        int kl = (t & 3) * 16 + j2;
        int kblk = kt * 2 + (kl >> 5);
        int lg = (kl >> 3) & 3;
        int j = kl & 7;
        int lane = ll + lg * 16;
        Wfrag[((long)kblk * 12 + ni) * 512 + lane * 8 + j] = tileT[n64][kl];
    }
}

// ---------------------------------------------------------------------------
// Kernel 2: proj v5. 1024 blocks x 256 thr (4 waves, K-split x4). Block owns
// 16 rows. A-frags direct from x (f32->bf16); B-frags = contiguous 1KB loads
// from Wfrag (L2). Merge partials in LDS; wave 0 epilogue.
// ---------------------------------------------------------------------------
__global__ __launch_bounds__(256, 4) void proj_mfma(
    const float* __restrict__ x, const short* __restrict__ Wfrag,
    short* __restrict__ qg, short* __restrict__ kg, short* __restrict__ vtg) {
    __shared__ float accL[3][12][4][64];   // waves 1..3 partials (36 KB)
    __shared__ short vL[64][20];           // v transpose staging

    int m0 = blockIdx.x * 16;
    int t = threadIdx.x;
    int w = t >> 6, l = t & 63;
    int ll = l & 15, lg = l >> 4;

    f32x4 acc[12] = {};

    const float* xrow = x + (long)(m0 + ll) * EMB;

    #pragma unroll 4
    for (int ki = 0; ki < 8; ++ki) {
        int k0 = w * 256 + ki * 32;
        int kblk = k0 >> 5;
        f32x4 a0 = *(const f32x4*)(xrow + k0 + lg * 8);
        f32x4 a1 = *(const f32x4*)(xrow + k0 + lg * 8 + 4);
        short8 af;
        #pragma unroll
        for (int j = 0; j < 4; ++j) { af[j] = f2bf(a0[j]); af[4 + j] = f2bf(a1[j]); }
        const short* wbase = Wfrag + (long)kblk * 12 * 512 + l * 8;
        #pragma unroll
        for (int ni = 0; ni < 12; ++ni) {
            short8 bf = *(const short8*)(wbase + ni * 512);
            acc[ni] = __builtin_amdgcn_mfma_f32_16x16x32_bf16(af, bf, acc[ni], 0, 0, 0);
        }
    }

    if (w != 0) {
        #pragma unroll
        for (int ni = 0; ni < 12; ++ni)
            #pragma unroll
            for (int r = 0; r < 4; ++r)
                accL[w - 1][ni][r][l] = acc[ni][r];
    }
    __syncthreads();
    if (w == 0) {
        #pragma unroll
        for (int w2 = 0; w2 < 3; ++w2)
            #pragma unroll
            for (int ni = 0; ni < 12; ++ni)
                #pragma unroll
                for (int r = 0; r < 4; ++r)
                    acc[ni][r] += accL[w2][ni][r][l];

        const float cs = 0.125f * 1.44269504088896f;
        int mrow = m0 + lg * 4;
        #pragma unroll
        for (int ni = 0; ni < 4; ++ni)
            #pragma unroll
            for (int r = 0; r < 4; ++r)
                qg[(long)(mrow + r) * HD + ni * 16 + ll] = f2bf(acc[ni][r] * cs);
        #pragma unroll
        for (int ni = 4; ni < 8; ++ni)
            #pragma unroll
            for (int r = 0; r < 4; ++r)
                kg[(long)(mrow + r) * HD + (ni - 4) * 16 + ll] = f2bf(acc[ni][r]);
        #pragma unroll
        for (int ni = 8; ni < 12; ++ni)
            #pragma unroll
            for (int r = 0; r < 4; ++r)
                vL[(ni - 8) * 16 + ll][lg * 4 + r] = f2bf(acc[ni][r]);
        // same-wave LDS read-back (in-order), transposed store
        int b = m0 >> 11, s0 = m0 & 2047;
        int d = l;
        short8 v0 = *(const short8*)(&vL[d][0]);
        short8 v1 = *(const short8*)(&vL[d][8]);
        *(short8*)(vtg + ((long)b * HD + d) * SEQ + s0)     = v0;
        *(short8*)(vtg + ((long)b * HD + d) * SEQ + s0 + 8) = v1;
    }
}

// ---------------------------------------------------------------------------
// Kernel 3: paired-tile attention, swapped QK^T, XCD-affinity grid (r24).
// 512 1D blocks: b = id&7 (XCD), pair = id>>3. 512 thr = 8 waves.
// ---------------------------------------------------------------------------
__global__ __launch_bounds__(512, 4) void attn_mfma(
    const short* __restrict__ qg, const short* __restrict__ kg,
    const short* __restrict__ vtg, float* __restrict__ out) {
    __shared__ short PLA[NSPL][16][72];
    __shared__ short PLB[NSPL][16][72];
    __shared__ float pO[NSPL][16][65];
    __shared__ float pLs[NSPL][16];

    int b    = blockIdx.x & 7;
    int pair = blockIdx.x >> 3;
    int qtA = pair;
    int qtB = 127 - pair;
    int q0A = qtA * QBLK, q0B = qtB * QBLK;
    int t = threadIdx.x;
    int w = t >> 6, l = t & 63;
    int ll = l & 15, lg = l >> 4;

    const short* qb = qg + (long)b * SEQ * HD;
    const short* kb = kg + (long)b * SEQ * HD;
    const short* vb = vtg + (long)b * HD * SEQ;

    short8 qfA[2], qfB[2];
    #pragma unroll
    for (int ks = 0; ks < 2; ++ks) {
        qfA[ks] = *(const short8*)(qb + (long)(q0A + ll) * HD + ks * 32 + lg * 8);
        qfB[ks] = *(const short8*)(qb + (long)(q0B + ll) * HD + ks * 32 + lg * 8);
    }

    f32x4 accA[4] = {}, accB[4] = {};
    float psA = 0.f, psB = 0.f;

    int nkvB = q0B / 64 + 1;

    for (int kt = w; kt < nkvB; kt += NSPL) {
        int kv0 = kt * 64;
        bool maskA = (kv0 + 63) > q0A;
        bool maskB = (kv0 + 63) > q0B;

        #pragma unroll
        for (int n = 0; n < 4; ++n) {
            const short* kr = kb + (long)(kv0 + n * 16 + ll) * HD + lg * 8;
            short8 kf0 = *(const short8*)(kr);
            short8 kf1 = *(const short8*)(kr + 32);
            int kvb = kv0 + n * 16 + lg * 4;

            f32x4 sA = {};
            sA = __builtin_amdgcn_mfma_f32_16x16x32_bf16(kf0, qfA[0], sA, 0, 0, 0);
            sA = __builtin_amdgcn_mfma_f32_16x16x32_bf16(kf1, qfA[1], sA, 0, 0, 0);
            short4v pkA;
            #pragma unroll
            for (int r = 0; r < 4; ++r) {
                float pv = __builtin_amdgcn_exp2f(sA[r]);
                if (maskA && (kvb + r > q0A + ll)) pv = 0.f;
                psA += pv;
                pkA[r] = f2bf(pv);
            }
            *(short4v*)(&PLA[w][ll][n * 16 + lg * 4]) = pkA;

            f32x4 sB = {};
            sB = __builtin_amdgcn_mfma_f32_16x16x32_bf16(kf0, qfB[0], sB, 0, 0, 0);
            sB = __builtin_amdgcn_mfma_f32_16x16x32_bf16(kf1, qfB[1], sB, 0, 0, 0);
            short4v pkB;
            #pragma unroll
            for (int r = 0; r < 4; ++r) {
                float pv = __builtin_amdgcn_exp2f(sB[r]);
                if (maskB && (kvb + r > q0B + ll)) pv = 0.f;
                psB += pv;
                pkB[r] = f2bf(pv);
            }
            *(short4v*)(&PLB[w][ll][n * 16 + lg * 4]) = pkB;
        }

        #pragma unroll
        for (int ks = 0; ks < 2; ++ks) {
            short8 pfA = *(const short8*)(&PLA[w][ll][ks * 32 + lg * 8]);
            short8 pfB = *(const short8*)(&PLB[w][ll][ks * 32 + lg * 8]);
            #pragma unroll
            for (int nd = 0; nd < 4; ++nd) {
                short8 vf = *(const short8*)(vb + (long)(nd * 16 + ll) * SEQ + kv0 + ks * 32 + lg * 8);
                accA[nd] = __builtin_amdgcn_mfma_f32_16x16x32_bf16(pfA, vf, accA[nd], 0, 0, 0);
                accB[nd] = __builtin_amdgcn_mfma_f32_16x16x32_bf16(pfB, vf, accB[nd], 0, 0, 0);
            }
        }
    }

    psA += __shfl_xor(psA, 16, 64);
    psA += __shfl_xor(psA, 32, 64);
    psB += __shfl_xor(psB, 16, 64);
    psB += __shfl_xor(psB, 32, 64);

    // ---- tile A ----
    #pragma unroll
    for (int nd = 0; nd < 4; ++nd)
        #pragma unroll
        for (int r = 0; r < 4; ++r)
            pO[w][lg * 4 + r][nd * 16 + ll] = accA[nd][r];
    if (lg == 0) pLs[w][ll] = psA;
    __syncthreads();
    {
        int q = t >> 5, d0 = (t & 31) * 2;
        float L = 0.f, o0 = 0.f, o1 = 0.f;
        #pragma unroll
        for (int w2 = 0; w2 < NSPL; ++w2) {
            L  += pLs[w2][q];
            o0 += pO[w2][q][d0];
            o1 += pO[w2][q][d0 + 1];
        }
        float inv = 1.0f / L;
        float* dst = out + (long)b * SEQ * HD + (long)(q0A + q) * HD + d0;
        dst[0] = o0 * inv; dst[1] = o1 * inv;
    }
    __syncthreads();

    // ---- tile B ----
    #pragma unroll
    for (int nd = 0; nd < 4; ++nd)
        #pragma unroll
        for (int r = 0; r < 4; ++r)
            pO[w][lg * 4 + r][nd * 16 + ll] = accB[nd][r];
    if (lg == 0) pLs[w][ll] = psB;
    __syncthreads();
    {
        int q = t >> 5, d0 = (t & 31) * 2;
        float L = 0.f, o0 = 0.f, o1 = 0.f;
        #pragma unroll
        for (int w2 = 0; w2 < NSPL; ++w2) {
            L  += pLs[w2][q];
            o0 += pO[w2][q][d0];
            o1 += pO[w2][q][d0 + 1];
        }
        float inv = 1.0f / L;
        float* dst = out + (long)b * SEQ * HD + (long)(q0B + q) * HD + d0;
        dst[0] = o0 * inv; dst[1] = o1 * inv;
    }
}

// ---------------------------------------------------------------------------
extern "C" void kernel_launch(void* const* d_in, const int* in_sizes, int n_in,
                              void* d_out, int out_size, void* d_ws, size_t ws_size,
                              hipStream_t stream) {
    const float* x  = (const float*)d_in[0];
    const float* Wq = (const float*)d_in[1];
    const float* Wk = (const float*)d_in[2];
    const float* Wv = (const float*)d_in[3];
    float* outp = (float*)d_out;

    short* Wfrag = (short*)d_ws;                                // 384 KB
    short* qg  = (short*)((char*)d_ws + 393216);                // 2 MB
    short* kg  = (short*)((char*)d_ws + 393216 + 2097152);      // 2 MB
    short* vtg = (short*)((char*)d_ws + 393216 + 2 * 2097152);  // 2 MB

    transpose_w<<<48, 256, 0, stream>>>(Wq, Wk, Wv, Wfrag);
    proj_mfma<<<BATCH * SEQ / 16, 256, 0, stream>>>(x, Wfrag, qg, kg, vtg);
    attn_mfma<<<SEQ / QBLK / 2 * BATCH, 512, 0, stream>>>(qg, kg, vtg, outp);
}